// Round 7
// baseline (250.035 us; speedup 1.0000x reference)
//
#include <hip/hip_runtime.h>
#include <hip/hip_bf16.h>

// Problem constants
#define NB 512     // batch
#define NP 1152    // primary capsules
#define NC 10      // digit capsules
#define ND 16      // output capsule dim
#define NI 8       // input capsule dim

constexpr int WAVES  = 8;                // R7: 512-thread blocks (8 waves)
constexpr int K_B    = 2;                // b's per lane (register loop)
constexpr int B_TILE = WAVES * 4 * K_B;  // 64 b per block (8 waves x 4 bsub x K_B)
constexpr int P_TILE = 8;                // p's per block
constexpr int NBLK_B = NB / B_TILE;      // 8
constexpr int NBLK_P = NP / P_TILE;      // 144 (%8==0 -> XCD affinity: XCD = pblk%8;
                                         //  same-pblk blocks are 144 apart -> same XCD -> W L2-local)
constexpr int SVD = NB * NC * ND;        // 81920
constexpr int W_TILE_BYTES = P_TILE * NC * ND * NI * 4;   // 40960
constexpr int X_TILE_FLOATS = B_TILE * P_TILE * NI;       // 4096 floats = 16KB

constexpr float LOG2E = 1.4426950408889634f;

typedef float v2f __attribute__((ext_vector_type(2)));

// 16-lane all-reduce sum via DPP (quad_perm xor1, xor2; row_ror 4, 8).
// Pure VALU. Result broadcast to all 16 lanes of the row.
__device__ __forceinline__ float red16_dpp(float v) {
    int t;
    t = __builtin_amdgcn_update_dpp(0, __float_as_int(v), 0xB1, 0xF, 0xF, true); // xor1
    v += __int_as_float(t);
    t = __builtin_amdgcn_update_dpp(0, __float_as_int(v), 0x4E, 0xF, 0xF, true); // xor2
    v += __int_as_float(t);
    t = __builtin_amdgcn_update_dpp(0, __float_as_int(v), 0x124, 0xF, 0xF, true); // row_ror:4
    v += __int_as_float(t);
    t = __builtin_amdgcn_update_dpp(0, __float_as_int(v), 0x128, 0xF, 0xF, true); // row_ror:8
    v += __int_as_float(t);
    return v;
}

// One routing pass. R7: occupancy via BIGGER BLOCKS, not smaller LDS.
// Hard-won laws from R0-R6:
//  - __launch_bounds__(B,w) => compiler VGPR cap = (64*B? no) ~ (B=256: 256/w);
//    kernel needs ~84-100 VGPR; cap below that => silent scratch spill
//    (signature: FETCH/WRITE x4-20, VALUBusy collapse). R1/R5/R6 all died of this.
//  - HW VGPR tier <=128 allows 4 waves/SIMD = 16 waves/CU; R3's 48KB LDS
//    capped it at 3 blocks x 4 waves = 12. Latency-bound scaling (8 w/CU ~97us,
//    12 w/CU ~72us) says waves/CU is the lever.
// R7: 512-thread blocks, per-thread code IDENTICAL to R3. LDS = 40KB W + 16KB x
// = 56KB -> 2 blocks/CU x 8 waves = 16 waves/CU. __launch_bounds__(512,4)
// -> cap 128, way above need -> no spill. W staging traffic also halves.
// Lane = (bsub 2b | d 4b); wave w handles b = w*8 + k*4 + bsub.
// W LDS swizzle involution: S(A) = A ^ (bit7(A)<<4) ^ (bit8(A)<<5).
//   Staging: LDS linear dest L <- global source S(L); reads issue S(A).
// x LDS swizzle (R4, verified): physical unit u holds logical (bl, w16^(bl&3))
//   -> read XOR (bsub<<4): bsub hits bank-quads {0,4,8,12}, conflict-free.
// Softmax slimming (R2, verified): log2(e) folded into vr, NO max-subtraction
// (|lg*log2e| <~ 50 << 127, exp2-safe), v_rcp_f32 for 1/sum.
// PASS 0: coup = 0.1;  PASS 1: logits = u.v0;  PASS 2: logits = u.(v0+v1)
template<int PASS>
__global__ __launch_bounds__(512, 4)
void caps_pass(const float* __restrict__ x,    // [NB, NP, NI]
               const float* __restrict__ w,    // [NP, NC, ND, NI]
               const float* __restrict__ v0,   // [NB, NC, ND]
               const float* __restrict__ v1,   // [NB, NC, ND]
               float* __restrict__ s_out)      // [NB, NC, ND]
{
    __shared__ __align__(16) float w_lds[W_TILE_BYTES / 4];   // 40KB
    __shared__ __align__(16) float x_lds[X_TILE_FLOATS];      // 16KB, [b][pp][i] swizzled

    const int tid  = threadIdx.x;
    const int lane = tid & 63;
    const int wave = tid >> 6;           // 0..7
    const int d    = lane & 15;
    const int bsub = lane >> 4;          // 0..3
    const int pblk = blockIdx.x % NBLK_P;
    const int bblk = blockIdx.x / NBLK_P;
    const int p0   = pblk * P_TILE;

    // ---- stage W tile: each wave loads one 5KB slice (16B/lane, linear dest) ----
    {
        const uint8_t* wsrc = (const uint8_t*)w + (size_t)pblk * W_TILE_BYTES;
        // source offset: S(lane*16) within the 1KB chunk (bits 7,8 of chunk bases are 0)
        const int lane_src = (lane << 4) ^ ((lane & 8) << 1) ^ ((lane & 16) << 1);
        #pragma unroll
        for (int j = 0; j < 5; ++j) {
            const int off = wave * 5120 + j * 1024;
            __builtin_amdgcn_global_load_lds(
                (const __attribute__((address_space(1))) void*)(wsrc + off + lane_src),
                (__attribute__((address_space(3))) void*)((uint8_t*)w_lds + off),
                16, 0, 0);
        }
    }

    // ---- stage x tile: 16KB, linear LDS dest, swizzled global source ----
    // 16B unit u (0..1023): bl = u>>4 (0..63), w16 = u&15 (= pp*2+half).
    // Physical LDS unit u holds logical unit (bl, w16 ^ (bl&3)) [byte bits 4-5].
    // Source strips stay 256B-contiguous per b.
    {
        #pragma unroll
        for (int j = 0; j < 2; ++j) {
            const int u   = wave * 128 + j * 64 + lane;
            const int bl  = u >> 4;
            const int w16 = u & 15;
            const float* bbase = x + ((size_t)(bblk * B_TILE + bl) * NP + p0) * NI;
            const uint8_t* src = (const uint8_t*)bbase + ((w16 ^ (bl & 3)) * 16);
            __builtin_amdgcn_global_load_lds(
                (const __attribute__((address_space(1))) void*)src,
                (__attribute__((address_space(3))) void*)((uint8_t*)x_lds + (size_t)u * 16),
                16, 0, 0);
        }
    }

    int bidx[K_B];
    #pragma unroll
    for (int k = 0; k < K_B; ++k) bidx[k] = bblk * B_TILE + wave * 8 + k * 4 + bsub;

    // v (v0, or v0+v1 for pass 2), pre-scaled by log2(e) — loop-invariant over p
    float vr[K_B][NC];
    if (PASS >= 1) {
        #pragma unroll
        for (int k = 0; k < K_B; ++k)
            #pragma unroll
            for (int c = 0; c < NC; ++c) {
                float vv = v0[(bidx[k] * NC + c) * ND + d];
                if (PASS == 2) vv += v1[(bidx[k] * NC + c) * ND + d];
                vr[k][c] = vv * LOG2E;
            }
    }

    float sacc[K_B][NC];
    #pragma unroll
    for (int k = 0; k < K_B; ++k)
        #pragma unroll
        for (int c = 0; c < NC; ++c) sacc[k][c] = 0.0f;

    // swizzled read offset for W[pp,c,d,0:4]: A = d*32 -> A ^ (bit2(d)<<4) ^ (bit3(d)<<5).
    // Half 2 at A+16 = lane_rd^16 (bit4 flip, bits 7,8 unchanged).
    const int lane_rd = (d << 5) ^ ((d & 4) << 2) ^ ((d & 8) << 2);
    const int xswz    = bsub << 4;   // x read swizzle (byte bits 4-5 ^= b&3)

    asm volatile("s_waitcnt vmcnt(0)" ::: "memory");   // W + x staging complete
    __syncthreads();                                   // all slices visible to all waves

    for (int pp = 0; pp < P_TILE; ++pp) {
        v2f xv[K_B][4];
        #pragma unroll
        for (int k = 0; k < K_B; ++k) {
            const int xb = ((wave * 8 + k * 4 + bsub) * 256 + pp * 32) ^ xswz;
            const uint8_t* xp = (const uint8_t*)x_lds;
            const float4 a = *(const float4*)(xp + xb);
            const float4 b = *(const float4*)(xp + (xb ^ 16));
            xv[k][0] = v2f{a.x, a.y};
            xv[k][1] = v2f{a.z, a.w};
            xv[k][2] = v2f{b.x, b.y};
            xv[k][3] = v2f{b.z, b.w};
        }

        float uh[K_B][NC];
        #pragma unroll
        for (int c = 0; c < NC; ++c) {
            const uint8_t* pb = (const uint8_t*)w_lds + pp * 5120 + c * 512;
            const float4 wa = *(const float4*)(pb + lane_rd);          // W[p,c,d,0:4]
            const float4 wb = *(const float4*)(pb + (lane_rd ^ 16));   // W[p,c,d,4:8]
            const v2f w01{wa.x, wa.y}, w23{wa.z, wa.w};
            const v2f w45{wb.x, wb.y}, w67{wb.z, wb.w};
            #pragma unroll
            for (int k = 0; k < K_B; ++k) {
                v2f acc = w01 * xv[k][0];                              // v_pk_mul_f32
                acc = __builtin_elementwise_fma(w23, xv[k][1], acc);   // v_pk_fma_f32
                acc = __builtin_elementwise_fma(w45, xv[k][2], acc);
                acc = __builtin_elementwise_fma(w67, xv[k][3], acc);
                const float u = acc[0] + acc[1];
                if (PASS == 0) sacc[k][c] = fmaf(0.1f, u, sacc[k][c]);
                else           uh[k][c] = u;
            }
        }

        if (PASS >= 1) {
            #pragma unroll
            for (int k = 0; k < K_B; ++k) {
                float lg[NC];
                #pragma unroll
                for (int c = 0; c < NC; ++c)
                    lg[c] = red16_dpp(uh[k][c] * vr[k][c]);   // log2-domain logits
                float ssum = 0.0f;
                float coup[NC];
                #pragma unroll
                for (int c = 0; c < NC; ++c) {
                    coup[c] = __builtin_amdgcn_exp2f(lg[c]);  // no max-sub: bounded
                    ssum += coup[c];
                }
                const float inv = __builtin_amdgcn_rcpf(ssum);
                #pragma unroll
                for (int c = 0; c < NC; ++c)
                    sacc[k][c] = fmaf(coup[c] * inv, uh[k][c], sacc[k][c]);
            }
        }
    }

    // tail: each thread owns distinct (b,d) -> 10 atomics per k, no redundancy
    #pragma unroll
    for (int k = 0; k < K_B; ++k)
        #pragma unroll
        for (int c = 0; c < NC; ++c)
            atomicAdd(&s_out[(bidx[k] * NC + c) * ND + d], sacc[k][c]);
}

// v = (|s|^2/(1+|s|^2)) * s / sqrt(|s|^2+1e-7), norm over d (16-lane rows).
// ZERO_S: re-zero s for the next routing pass (replaces a hipMemsetAsync).
template<bool ZERO_S>
__global__ __launch_bounds__(256)
void caps_squash(float* __restrict__ s, float* __restrict__ v)
{
    const int idx = blockIdx.x * 256 + threadIdx.x;
    const float sv = s[idx];
    if (ZERO_S) s[idx] = 0.0f;
    float sq = red16_dpp(sv * sv);
    const float scale = (sq / (1.0f + sq)) / sqrtf(sq + 1e-7f);
    v[idx] = scale * sv;
}

extern "C" void kernel_launch(void* const* d_in, const int* in_sizes, int n_in,
                              void* d_out, int out_size, void* d_ws, size_t ws_size,
                              hipStream_t stream)
{
    const float* x = (const float*)d_in[0];
    const float* w = (const float*)d_in[1];
    float* out = (float*)d_out;

    float* s  = (float*)d_ws;       // [NB,NC,ND]
    float* v0 = s + SVD;            // [NB,NC,ND]
    float* v1 = out;                // reuse output buffer (overwritten by final squash)

    const dim3 pgrid(NBLK_B * NBLK_P);   // 1152 blocks of 512
    const dim3 pblock(512);
    const dim3 qgrid(SVD / 256);         // 320
    const dim3 qblock(256);

    hipMemsetAsync(s, 0, (size_t)SVD * sizeof(float), stream);
    caps_pass<0><<<pgrid, pblock, 0, stream>>>(x, w, nullptr, nullptr, s);
    caps_squash<true><<<qgrid, qblock, 0, stream>>>(s, v0);
    caps_pass<1><<<pgrid, pblock, 0, stream>>>(x, w, v0, nullptr, s);
    caps_squash<true><<<qgrid, qblock, 0, stream>>>(s, v1);
    caps_pass<2><<<pgrid, pblock, 0, stream>>>(x, w, v0, v1, s);
    caps_squash<false><<<qgrid, qblock, 0, stream>>>(s, out);
}

// Round 8
// 231.096 us; speedup vs baseline: 1.0819x; 1.0819x over previous
//
#include <hip/hip_runtime.h>
#include <hip/hip_bf16.h>

// Problem constants
#define NB 512     // batch
#define NP 1152    // primary capsules
#define NC 10      // digit capsules
#define ND 16      // output capsule dim
#define NI 8       // input capsule dim

constexpr int WAVES  = 8;                // 512-thread blocks (8 waves)
constexpr int K_B    = 2;                // b's per lane (register loop)
constexpr int B_TILE = WAVES * 4 * K_B;  // 64 b per block (8 waves x 4 bsub x K_B)
constexpr int P_TILE = 8;                // p's per block
constexpr int NBLK_B = NB / B_TILE;      // 8
constexpr int NBLK_P = NP / P_TILE;      // 144 (%8==0 -> XCD affinity: XCD = pblk%8;
                                         //  same-pblk blocks are 144 apart -> same XCD -> W L2-local)
constexpr int SVD = NB * NC * ND;        // 81920
constexpr int W_TILE_BYTES = P_TILE * NC * ND * NI * 4;   // 40960
constexpr int X_TILE_FLOATS = B_TILE * P_TILE * NI;       // 4096 floats = 16KB

constexpr float LOG2E = 1.4426950408889634f;

typedef float v2f __attribute__((ext_vector_type(2)));

// 16-lane all-reduce sum via DPP (quad_perm xor1, xor2; row_ror 4, 8).
// Pure VALU. Result broadcast to all 16 lanes of the row.
__device__ __forceinline__ float red16_dpp(float v) {
    int t;
    t = __builtin_amdgcn_update_dpp(0, __float_as_int(v), 0xB1, 0xF, 0xF, true); // xor1
    v += __int_as_float(t);
    t = __builtin_amdgcn_update_dpp(0, __float_as_int(v), 0x4E, 0xF, 0xF, true); // xor2
    v += __int_as_float(t);
    t = __builtin_amdgcn_update_dpp(0, __float_as_int(v), 0x124, 0xF, 0xF, true); // row_ror:4
    v += __int_as_float(t);
    t = __builtin_amdgcn_update_dpp(0, __float_as_int(v), 0x128, 0xF, 0xF, true); // row_ror:8
    v += __int_as_float(t);
    return v;
}

// One routing pass. R8 = R7 structure with the VGPR cap FIXED.
// VGPR-cap law (confirmed 4x): __launch_bounds__(_, N) => compiler VGPR cap
// = 256/N, INDEPENDENT of block size: (256,2)->128, (256,3)->84, (256,5)->48,
// (512,4)->64. Kernel's natural demand ~72-84 (R3 measured 68-72). Any cap
// below demand => silent scratch spill (signature: FETCH/WRITE inflation,
// VALUBusy drop). R1/R5/R6/R7 all lost to this.
// R8: (512,2) -> cap 128 >> demand -> no spill. HW occupancy comes from HW
// tiers, not the bounds arg: VGPR<=128 -> 4 waves/SIMD; LDS 56KB -> 2 blocks
// x 8 waves = 16 waves/CU (R3 had 12). R7 proved the mechanism: even WITH
// spill, 16-wave blocks beat R6 (98 vs 111us) at occupancy 33.6% (best yet).
// Lane = (bsub 2b | d 4b); wave w handles b = w*8 + k*4 + bsub.
// W LDS swizzle involution: S(A) = A ^ (bit7(A)<<4) ^ (bit8(A)<<5).
//   Staging: LDS linear dest L <- global source S(L); reads issue S(A).
// x LDS swizzle (R4, verified): physical unit u holds logical (bl, w16^(bl&3))
//   -> read XOR (bsub<<4): bsub hits bank-quads {0,4,8,12}, conflict-free.
// Softmax slimming (R2, verified): log2(e) folded into vr, NO max-subtraction
// (|lg*log2e| <~ 50 << 127, exp2-safe), v_rcp_f32 for 1/sum.
// PASS 0: coup = 0.1;  PASS 1: logits = u.v0;  PASS 2: logits = u.(v0+v1)
template<int PASS>
__global__ __launch_bounds__(512, 2)
void caps_pass(const float* __restrict__ x,    // [NB, NP, NI]
               const float* __restrict__ w,    // [NP, NC, ND, NI]
               const float* __restrict__ v0,   // [NB, NC, ND]
               const float* __restrict__ v1,   // [NB, NC, ND]
               float* __restrict__ s_out)      // [NB, NC, ND]
{
    __shared__ __align__(16) float w_lds[W_TILE_BYTES / 4];   // 40KB
    __shared__ __align__(16) float x_lds[X_TILE_FLOATS];      // 16KB, [b][pp][i] swizzled

    const int tid  = threadIdx.x;
    const int lane = tid & 63;
    const int wave = tid >> 6;           // 0..7
    const int d    = lane & 15;
    const int bsub = lane >> 4;          // 0..3
    const int pblk = blockIdx.x % NBLK_P;
    const int bblk = blockIdx.x / NBLK_P;
    const int p0   = pblk * P_TILE;

    // ---- stage W tile: each wave loads one 5KB slice (16B/lane, linear dest) ----
    {
        const uint8_t* wsrc = (const uint8_t*)w + (size_t)pblk * W_TILE_BYTES;
        // source offset: S(lane*16) within the 1KB chunk (bits 7,8 of chunk bases are 0)
        const int lane_src = (lane << 4) ^ ((lane & 8) << 1) ^ ((lane & 16) << 1);
        #pragma unroll
        for (int j = 0; j < 5; ++j) {
            const int off = wave * 5120 + j * 1024;
            __builtin_amdgcn_global_load_lds(
                (const __attribute__((address_space(1))) void*)(wsrc + off + lane_src),
                (__attribute__((address_space(3))) void*)((uint8_t*)w_lds + off),
                16, 0, 0);
        }
    }

    // ---- stage x tile: 16KB, linear LDS dest, swizzled global source ----
    // 16B unit u (0..1023): bl = u>>4 (0..63), w16 = u&15 (= pp*2+half).
    // Physical LDS unit u holds logical unit (bl, w16 ^ (bl&3)) [byte bits 4-5].
    // Source strips stay 256B-contiguous per b.
    {
        #pragma unroll
        for (int j = 0; j < 2; ++j) {
            const int u   = wave * 128 + j * 64 + lane;
            const int bl  = u >> 4;
            const int w16 = u & 15;
            const float* bbase = x + ((size_t)(bblk * B_TILE + bl) * NP + p0) * NI;
            const uint8_t* src = (const uint8_t*)bbase + ((w16 ^ (bl & 3)) * 16);
            __builtin_amdgcn_global_load_lds(
                (const __attribute__((address_space(1))) void*)src,
                (__attribute__((address_space(3))) void*)((uint8_t*)x_lds + (size_t)u * 16),
                16, 0, 0);
        }
    }

    int bidx[K_B];
    #pragma unroll
    for (int k = 0; k < K_B; ++k) bidx[k] = bblk * B_TILE + wave * 8 + k * 4 + bsub;

    // v (v0, or v0+v1 for pass 2), pre-scaled by log2(e) — loop-invariant over p
    float vr[K_B][NC];
    if (PASS >= 1) {
        #pragma unroll
        for (int k = 0; k < K_B; ++k)
            #pragma unroll
            for (int c = 0; c < NC; ++c) {
                float vv = v0[(bidx[k] * NC + c) * ND + d];
                if (PASS == 2) vv += v1[(bidx[k] * NC + c) * ND + d];
                vr[k][c] = vv * LOG2E;
            }
    }

    float sacc[K_B][NC];
    #pragma unroll
    for (int k = 0; k < K_B; ++k)
        #pragma unroll
        for (int c = 0; c < NC; ++c) sacc[k][c] = 0.0f;

    // swizzled read offset for W[pp,c,d,0:4]: A = d*32 -> A ^ (bit2(d)<<4) ^ (bit3(d)<<5).
    // Half 2 at A+16 = lane_rd^16 (bit4 flip, bits 7,8 unchanged).
    const int lane_rd = (d << 5) ^ ((d & 4) << 2) ^ ((d & 8) << 2);
    const int xswz    = bsub << 4;   // x read swizzle (byte bits 4-5 ^= b&3)

    asm volatile("s_waitcnt vmcnt(0)" ::: "memory");   // W + x staging complete
    __syncthreads();                                   // all slices visible to all waves

    for (int pp = 0; pp < P_TILE; ++pp) {
        v2f xv[K_B][4];
        #pragma unroll
        for (int k = 0; k < K_B; ++k) {
            const int xb = ((wave * 8 + k * 4 + bsub) * 256 + pp * 32) ^ xswz;
            const uint8_t* xp = (const uint8_t*)x_lds;
            const float4 a = *(const float4*)(xp + xb);
            const float4 b = *(const float4*)(xp + (xb ^ 16));
            xv[k][0] = v2f{a.x, a.y};
            xv[k][1] = v2f{a.z, a.w};
            xv[k][2] = v2f{b.x, b.y};
            xv[k][3] = v2f{b.z, b.w};
        }

        float uh[K_B][NC];
        #pragma unroll
        for (int c = 0; c < NC; ++c) {
            const uint8_t* pb = (const uint8_t*)w_lds + pp * 5120 + c * 512;
            const float4 wa = *(const float4*)(pb + lane_rd);          // W[p,c,d,0:4]
            const float4 wb = *(const float4*)(pb + (lane_rd ^ 16));   // W[p,c,d,4:8]
            const v2f w01{wa.x, wa.y}, w23{wa.z, wa.w};
            const v2f w45{wb.x, wb.y}, w67{wb.z, wb.w};
            #pragma unroll
            for (int k = 0; k < K_B; ++k) {
                v2f acc = w01 * xv[k][0];                              // v_pk_mul_f32
                acc = __builtin_elementwise_fma(w23, xv[k][1], acc);   // v_pk_fma_f32
                acc = __builtin_elementwise_fma(w45, xv[k][2], acc);
                acc = __builtin_elementwise_fma(w67, xv[k][3], acc);
                const float u = acc[0] + acc[1];
                if (PASS == 0) sacc[k][c] = fmaf(0.1f, u, sacc[k][c]);
                else           uh[k][c] = u;
            }
        }

        if (PASS >= 1) {
            #pragma unroll
            for (int k = 0; k < K_B; ++k) {
                float lg[NC];
                #pragma unroll
                for (int c = 0; c < NC; ++c)
                    lg[c] = red16_dpp(uh[k][c] * vr[k][c]);   // log2-domain logits
                float ssum = 0.0f;
                float coup[NC];
                #pragma unroll
                for (int c = 0; c < NC; ++c) {
                    coup[c] = __builtin_amdgcn_exp2f(lg[c]);  // no max-sub: bounded
                    ssum += coup[c];
                }
                const float inv = __builtin_amdgcn_rcpf(ssum);
                #pragma unroll
                for (int c = 0; c < NC; ++c)
                    sacc[k][c] = fmaf(coup[c] * inv, uh[k][c], sacc[k][c]);
            }
        }
    }

    // tail: each thread owns distinct (b,d) -> 10 atomics per k, no redundancy
    #pragma unroll
    for (int k = 0; k < K_B; ++k)
        #pragma unroll
        for (int c = 0; c < NC; ++c)
            atomicAdd(&s_out[(bidx[k] * NC + c) * ND + d], sacc[k][c]);
}

// v = (|s|^2/(1+|s|^2)) * s / sqrt(|s|^2+1e-7), norm over d (16-lane rows).
// ZERO_S: re-zero s for the next routing pass (replaces a hipMemsetAsync).
template<bool ZERO_S>
__global__ __launch_bounds__(256)
void caps_squash(float* __restrict__ s, float* __restrict__ v)
{
    const int idx = blockIdx.x * 256 + threadIdx.x;
    const float sv = s[idx];
    if (ZERO_S) s[idx] = 0.0f;
    float sq = red16_dpp(sv * sv);
    const float scale = (sq / (1.0f + sq)) / sqrtf(sq + 1e-7f);
    v[idx] = scale * sv;
}

extern "C" void kernel_launch(void* const* d_in, const int* in_sizes, int n_in,
                              void* d_out, int out_size, void* d_ws, size_t ws_size,
                              hipStream_t stream)
{
    const float* x = (const float*)d_in[0];
    const float* w = (const float*)d_in[1];
    float* out = (float*)d_out;

    float* s  = (float*)d_ws;       // [NB,NC,ND]
    float* v0 = s + SVD;            // [NB,NC,ND]
    float* v1 = out;                // reuse output buffer (overwritten by final squash)

    const dim3 pgrid(NBLK_B * NBLK_P);   // 1152 blocks of 512
    const dim3 pblock(512);
    const dim3 qgrid(SVD / 256);         // 320
    const dim3 qblock(256);

    hipMemsetAsync(s, 0, (size_t)SVD * sizeof(float), stream);
    caps_pass<0><<<pgrid, pblock, 0, stream>>>(x, w, nullptr, nullptr, s);
    caps_squash<true><<<qgrid, qblock, 0, stream>>>(s, v0);
    caps_pass<1><<<pgrid, pblock, 0, stream>>>(x, w, v0, nullptr, s);
    caps_squash<true><<<qgrid, qblock, 0, stream>>>(s, v1);
    caps_pass<2><<<pgrid, pblock, 0, stream>>>(x, w, v0, v1, s);
    caps_squash<false><<<qgrid, qblock, 0, stream>>>(s, out);
}

// Round 9
// 180.734 us; speedup vs baseline: 1.3834x; 1.2787x over previous
//
#include <hip/hip_runtime.h>
#include <hip/hip_bf16.h>

// Problem constants
#define NB 512     // batch
#define NP 1152    // primary capsules
#define NC 10      // digit capsules
#define ND 16      // output capsule dim
#define NI 8       // input capsule dim

constexpr int K_B    = 2;                // b's per lane
constexpr int B_TILE = 4 * 4 * K_B;      // 32 b per block (4 waves x 4 bsub x K_B)
constexpr int P_TILE = 8;                // p's per block
constexpr int NBLK_B = NB / B_TILE;      // 16
constexpr int NBLK_P = NP / P_TILE;      // 144
constexpr int SVD = NB * NC * ND;        // 81920
constexpr int W_TILE_BYTES = P_TILE * NC * ND * NI * 4;   // 40960
constexpr int X_TILE_FLOATS = B_TILE * P_TILE * NI;       // 2048 floats = 8KB

constexpr float LOG2E = 1.4426950408889634f;

typedef float v2f __attribute__((ext_vector_type(2)));

// 16-lane all-reduce sum via DPP (quad_perm xor1, xor2; row_ror 4, 8).
// Pure VALU. Result broadcast to all 16 lanes of the row.
__device__ __forceinline__ float red16_dpp(float v) {
    int t;
    t = __builtin_amdgcn_update_dpp(0, __float_as_int(v), 0xB1, 0xF, 0xF, true); // xor1
    v += __int_as_float(t);
    t = __builtin_amdgcn_update_dpp(0, __float_as_int(v), 0x4E, 0xF, 0xF, true); // xor2
    v += __int_as_float(t);
    t = __builtin_amdgcn_update_dpp(0, __float_as_int(v), 0x124, 0xF, 0xF, true); // row_ror:4
    v += __int_as_float(t);
    t = __builtin_amdgcn_update_dpp(0, __float_as_int(v), 0x128, 0xF, 0xF, true); // row_ror:8
    v += __int_as_float(t);
    return v;
}

// One routing pass. R9: ATTACK THE ATOMIC TAIL, keep the proven R3 structure.
// Evidence chain R3-R8: pass0 (VALU 20%) == pass1 (VALU 56%) == ~73us at every
// occupancy tried -> neither VALU, LDS, nor waves/CU is the floor.
// WRITE_SIZE = 46080KB = EXACTLY 11.8M x 4B = one HBM write per atomicAdd
// (81920 outputs x 144 contending p-blocks). Old grid: consecutive ids = same
// bblk -> round-robin puts the 144 contenders for each address on ALL 8 XCDs;
// per-XCD L2s aren't coherent, so every device-scope atomic resolves at the
// far coherence point and writes through. 11.8M far-atomics ~= the 73us floor.
// R9 grid swizzle: bblk = id%16, pblk = id/16 -> id === bblk (mod 8) -> all
// 144 blocks updating a given b-slice land on ONE XCD; s_out lines stay dirty
// in that L2, atomics complete locally, one writeback. Bonus: those blocks
// share the same 1.2MB x-slice (L2-local). W (5.9MB) is absorbed by L3.
// __launch_bounds__(256,2): cap-law (256/N) -> 128 >> demand ~72-90, no spill;
// HW residency stays LDS-capped at 3 blocks/CU (= R3).
// Lane = (bsub 2b | d 4b); wave w handles b = w*8 + k*4 + bsub.
// W LDS swizzle involution: S(A) = A ^ (bit7(A)<<4) ^ (bit8(A)<<5).
// x LDS swizzle (R4, verified): physical unit u holds logical (bl, w16^(bl&3))
//   -> read XOR (bsub<<4): bsub hits bank-quads {0,4,8,12}, conflict-free.
// Softmax slimming (R2, verified): log2(e) folded into vr, NO max-subtraction
// (|lg*log2e| <~ 50 << 127, exp2-safe), v_rcp_f32 for 1/sum.
// PASS 0: coup = 0.1;  PASS 1: logits = u.v0;  PASS 2: logits = u.(v0+v1)
template<int PASS>
__global__ __launch_bounds__(256, 2)
void caps_pass(const float* __restrict__ x,    // [NB, NP, NI]
               const float* __restrict__ w,    // [NP, NC, ND, NI]
               const float* __restrict__ v0,   // [NB, NC, ND]
               const float* __restrict__ v1,   // [NB, NC, ND]
               float* __restrict__ s_out)      // [NB, NC, ND]
{
    __shared__ __align__(16) float w_lds[W_TILE_BYTES / 4];   // 40KB
    __shared__ __align__(16) float x_lds[X_TILE_FLOATS];      // 8KB, [b][pp][i] swizzled

    const int tid  = threadIdx.x;
    const int lane = tid & 63;
    const int wave = tid >> 6;           // 0..3
    const int d    = lane & 15;
    const int bsub = lane >> 4;          // 0..3
    // R9 swizzle: id = pblk*16 + bblk -> id%8 = bblk%8 -> per-bblk XCD affinity.
    const int bblk = blockIdx.x % NBLK_B;
    const int pblk = blockIdx.x / NBLK_B;
    const int p0   = pblk * P_TILE;

    // ---- stage W tile: each wave loads one 10KB quarter (16B/lane, linear dest) ----
    {
        const uint8_t* wsrc = (const uint8_t*)w + (size_t)pblk * W_TILE_BYTES;
        // source offset: S(lane*16) within the 1KB chunk (bits 7,8 of chunk bases are 0)
        const int lane_src = (lane << 4) ^ ((lane & 8) << 1) ^ ((lane & 16) << 1);
        #pragma unroll
        for (int j = 0; j < 10; ++j) {
            const int off = wave * 10240 + j * 1024;
            __builtin_amdgcn_global_load_lds(
                (const __attribute__((address_space(1))) void*)(wsrc + off + lane_src),
                (__attribute__((address_space(3))) void*)((uint8_t*)w_lds + off),
                16, 0, 0);
        }
    }

    // ---- stage x tile: 8KB, linear LDS dest, swizzled global source ----
    // 16B unit u (0..511): bl = u>>4 (0..31), w16 = u&15 (= pp*2+half).
    // Physical LDS unit u holds logical unit (bl, w16 ^ (bl&3)) [byte bits 4-5].
    // Source strips stay 256B-contiguous per b.
    {
        #pragma unroll
        for (int j = 0; j < 2; ++j) {
            const int u   = wave * 128 + j * 64 + lane;
            const int bl  = u >> 4;
            const int w16 = u & 15;
            const float* bbase = x + ((size_t)(bblk * B_TILE + bl) * NP + p0) * NI;
            const uint8_t* src = (const uint8_t*)bbase + ((w16 ^ (bl & 3)) * 16);
            __builtin_amdgcn_global_load_lds(
                (const __attribute__((address_space(1))) void*)src,
                (__attribute__((address_space(3))) void*)((uint8_t*)x_lds + (size_t)u * 16),
                16, 0, 0);
        }
    }

    int bidx[K_B];
    #pragma unroll
    for (int k = 0; k < K_B; ++k) bidx[k] = bblk * B_TILE + wave * 8 + k * 4 + bsub;

    // v (v0, or v0+v1 for pass 2), pre-scaled by log2(e) — loop-invariant over p
    float vr[K_B][NC];
    if (PASS >= 1) {
        #pragma unroll
        for (int k = 0; k < K_B; ++k)
            #pragma unroll
            for (int c = 0; c < NC; ++c) {
                float vv = v0[(bidx[k] * NC + c) * ND + d];
                if (PASS == 2) vv += v1[(bidx[k] * NC + c) * ND + d];
                vr[k][c] = vv * LOG2E;
            }
    }

    float sacc[K_B][NC];
    #pragma unroll
    for (int k = 0; k < K_B; ++k)
        #pragma unroll
        for (int c = 0; c < NC; ++c) sacc[k][c] = 0.0f;

    // swizzled read offset for W[pp,c,d,0:4]: A = d*32 -> A ^ (bit2(d)<<4) ^ (bit3(d)<<5).
    // Half 2 at A+16 = lane_rd^16 (bit4 flip, bits 7,8 unchanged).
    const int lane_rd = (d << 5) ^ ((d & 4) << 2) ^ ((d & 8) << 2);
    const int xswz    = bsub << 4;   // x read swizzle (byte bits 4-5 ^= b&3)

    asm volatile("s_waitcnt vmcnt(0)" ::: "memory");   // W + x staging complete
    __syncthreads();                                   // all quarters visible to all waves

    for (int pp = 0; pp < P_TILE; ++pp) {
        v2f xv[K_B][4];
        #pragma unroll
        for (int k = 0; k < K_B; ++k) {
            const int xb = ((wave * 8 + k * 4 + bsub) * 256 + pp * 32) ^ xswz;
            const uint8_t* xp = (const uint8_t*)x_lds;
            const float4 a = *(const float4*)(xp + xb);
            const float4 b = *(const float4*)(xp + (xb ^ 16));
            xv[k][0] = v2f{a.x, a.y};
            xv[k][1] = v2f{a.z, a.w};
            xv[k][2] = v2f{b.x, b.y};
            xv[k][3] = v2f{b.z, b.w};
        }

        float uh[K_B][NC];
        #pragma unroll
        for (int c = 0; c < NC; ++c) {
            const uint8_t* pb = (const uint8_t*)w_lds + pp * 5120 + c * 512;
            const float4 wa = *(const float4*)(pb + lane_rd);          // W[p,c,d,0:4]
            const float4 wb = *(const float4*)(pb + (lane_rd ^ 16));   // W[p,c,d,4:8]
            const v2f w01{wa.x, wa.y}, w23{wa.z, wa.w};
            const v2f w45{wb.x, wb.y}, w67{wb.z, wb.w};
            #pragma unroll
            for (int k = 0; k < K_B; ++k) {
                v2f acc = w01 * xv[k][0];                              // v_pk_mul_f32
                acc = __builtin_elementwise_fma(w23, xv[k][1], acc);   // v_pk_fma_f32
                acc = __builtin_elementwise_fma(w45, xv[k][2], acc);
                acc = __builtin_elementwise_fma(w67, xv[k][3], acc);
                const float u = acc[0] + acc[1];
                if (PASS == 0) sacc[k][c] = fmaf(0.1f, u, sacc[k][c]);
                else           uh[k][c] = u;
            }
        }

        if (PASS >= 1) {
            #pragma unroll
            for (int k = 0; k < K_B; ++k) {
                float lg[NC];
                #pragma unroll
                for (int c = 0; c < NC; ++c)
                    lg[c] = red16_dpp(uh[k][c] * vr[k][c]);   // log2-domain logits
                float ssum = 0.0f;
                float coup[NC];
                #pragma unroll
                for (int c = 0; c < NC; ++c) {
                    coup[c] = __builtin_amdgcn_exp2f(lg[c]);  // no max-sub: bounded
                    ssum += coup[c];
                }
                const float inv = __builtin_amdgcn_rcpf(ssum);
                #pragma unroll
                for (int c = 0; c < NC; ++c)
                    sacc[k][c] = fmaf(coup[c] * inv, uh[k][c], sacc[k][c]);
            }
        }
    }

    // tail: each thread owns distinct (b,d) -> 10 atomics per k, no redundancy.
    // With the R9 swizzle these resolve in the home XCD's L2 (all contenders
    // for a given address run on the same XCD).
    #pragma unroll
    for (int k = 0; k < K_B; ++k)
        #pragma unroll
        for (int c = 0; c < NC; ++c)
            atomicAdd(&s_out[(bidx[k] * NC + c) * ND + d], sacc[k][c]);
}

// v = (|s|^2/(1+|s|^2)) * s / sqrt(|s|^2+1e-7), norm over d (16-lane rows).
// ZERO_S: re-zero s for the next routing pass (replaces a hipMemsetAsync).
template<bool ZERO_S>
__global__ __launch_bounds__(256)
void caps_squash(float* __restrict__ s, float* __restrict__ v)
{
    const int idx = blockIdx.x * 256 + threadIdx.x;
    const float sv = s[idx];
    if (ZERO_S) s[idx] = 0.0f;
    float sq = red16_dpp(sv * sv);
    const float scale = (sq / (1.0f + sq)) / sqrtf(sq + 1e-7f);
    v[idx] = scale * sv;
}

extern "C" void kernel_launch(void* const* d_in, const int* in_sizes, int n_in,
                              void* d_out, int out_size, void* d_ws, size_t ws_size,
                              hipStream_t stream)
{
    const float* x = (const float*)d_in[0];
    const float* w = (const float*)d_in[1];
    float* out = (float*)d_out;

    float* s  = (float*)d_ws;       // [NB,NC,ND]
    float* v0 = s + SVD;            // [NB,NC,ND]
    float* v1 = out;                // reuse output buffer (overwritten by final squash)

    const dim3 pgrid(NBLK_B * NBLK_P);   // 2304 blocks of 256
    const dim3 pblock(256);
    const dim3 qgrid(SVD / 256);         // 320
    const dim3 qblock(256);

    hipMemsetAsync(s, 0, (size_t)SVD * sizeof(float), stream);
    caps_pass<0><<<pgrid, pblock, 0, stream>>>(x, w, nullptr, nullptr, s);
    caps_squash<true><<<qgrid, qblock, 0, stream>>>(s, v0);
    caps_pass<1><<<pgrid, pblock, 0, stream>>>(x, w, v0, nullptr, s);
    caps_squash<true><<<qgrid, qblock, 0, stream>>>(s, v1);
    caps_pass<2><<<pgrid, pblock, 0, stream>>>(x, w, v0, v1, s);
    caps_squash<false><<<qgrid, qblock, 0, stream>>>(s, out);
}